// Round 1
// baseline (14240.015 us; speedup 1.0000x reference)
//
#include <hip/hip_runtime.h>
#include <hip/hip_bf16.h>

#define BB 256
#define TT 512
#define DD 512
#define HH 1024
#define OO 512

typedef unsigned short u16;
typedef unsigned int u32;
typedef unsigned long long u64;
typedef __attribute__((ext_vector_type(8))) short frag8;
typedef __attribute__((ext_vector_type(4))) float floatx4;

__device__ __forceinline__ u16 f2b(float f) {
  union { float f; u32 u; } v; v.f = f;
  u32 r = v.u + 0x7fffu + ((v.u >> 16) & 1u);
  return (u16)(r >> 16);
}
__device__ __forceinline__ float b2f(u16 b) {
  union { u32 u; float f; } v; v.u = ((u32)b) << 16; return v.f;
}

// transpose f32 [K][N] -> bf16 [N][K]
__global__ void k_transpose(const float* __restrict__ src, u16* __restrict__ dst,
                            int K, int N) {
  int idx = blockIdx.x * 256 + threadIdx.x;
  if (idx >= K * N) return;
  int k = idx / N, n = idx - k * N;
  dst[(u64)n * K + k] = f2b(src[idx]);
}

__global__ void k_init_s0(const float* __restrict__ h0, u16* __restrict__ S) {
  int idx = blockIdx.x * 256 + threadIdx.x;
  if (idx < BB * HH) S[idx] = f2b(h0[idx]);
}

__global__ void k_final_h(const u16* __restrict__ Sl, float* __restrict__ out) {
  int idx = blockIdx.x * 256 + threadIdx.x;
  if (idx < BB * HH) out[idx] = b2f(Sl[idx]);
}

// ---------------------------------------------------------------------------
// GEMM1: Z = X @ W_xh.  X f32 [B*T, D] row-major (m = b*T + t).
// Wt bf16 [N=HH][K=DD].  Output scattered bf16 into S[t+1][b][col].
// 64x64 tile, 4 waves, each wave does 64x16 via 4x mfma_16x16x32_bf16.
// ---------------------------------------------------------------------------
__global__ __launch_bounds__(256) void k_gemm_xh(const float* __restrict__ X,
                                                 const u16* __restrict__ Wt,
                                                 u16* __restrict__ S) {
  __shared__ __align__(16) u16 As[64 * 72];  // +8 bf16 pad -> 2-way max conflicts
  __shared__ __align__(16) u16 Bs[64 * 72];
  const int tid = threadIdx.x;
  const int m0 = blockIdx.x * 64, n0 = blockIdx.y * 64;
  const int lane = tid & 63, wv = tid >> 6;
  const int fr = lane & 15, quad = lane >> 4;

  floatx4 acc[4];
#pragma unroll
  for (int i = 0; i < 4; ++i) acc[i] = (floatx4){0.f, 0.f, 0.f, 0.f};

  for (int kc = 0; kc < DD; kc += 64) {
    const float* Ab = X + (u64)m0 * DD + kc;
#pragma unroll
    for (int it = 0; it < 4; ++it) {
      int linear = (it * 256 + tid) * 4;
      int r = linear >> 6, c = linear & 63;
      float4 v = *(const float4*)(Ab + (u64)r * DD + c);
      ushort4 o;
      o.x = f2b(v.x); o.y = f2b(v.y); o.z = f2b(v.z); o.w = f2b(v.w);
      *(ushort4*)&As[r * 72 + c] = o;
    }
    const u16* Bb = Wt + (u64)n0 * DD + kc;
#pragma unroll
    for (int it = 0; it < 2; ++it) {
      int linear = (it * 256 + tid) * 8;
      int n = linear >> 6, c = linear & 63;
      *(uint4*)&Bs[n * 72 + c] = *(const uint4*)(Bb + (u64)n * DD + c);
    }
    __syncthreads();
#pragma unroll
    for (int kk = 0; kk < 64; kk += 32) {
      frag8 bf = *(const frag8*)&Bs[(wv * 16 + fr) * 72 + kk + quad * 8];
#pragma unroll
      for (int i = 0; i < 4; ++i) {
        frag8 af = *(const frag8*)&As[(i * 16 + fr) * 72 + kk + quad * 8];
        acc[i] = __builtin_amdgcn_mfma_f32_16x16x32_bf16(af, bf, acc[i], 0, 0, 0);
      }
    }
    __syncthreads();
  }
  const int col = n0 + wv * 16 + fr;
#pragma unroll
  for (int i = 0; i < 4; ++i) {
#pragma unroll
    for (int r = 0; r < 4; ++r) {
      int m = m0 + i * 16 + quad * 4 + r;
      int t = m & (TT - 1);
      int b = m >> 9;  // m / TT
      S[((u64)(t + 1) * BB + b) * HH + col] = f2b(acc[i][r]);
    }
  }
}

// ---------------------------------------------------------------------------
// Step: S[t+1] = tanh(S[t] @ W_hh + S[t+1])  (in-place over the Z values)
// A bf16 [BB][HH], Wt bf16 [HH][HH] ([N][K]).
// ---------------------------------------------------------------------------
__global__ __launch_bounds__(256) void k_step(const u16* __restrict__ Ht,
                                              const u16* __restrict__ Wt,
                                              u16* __restrict__ Zs) {
  __shared__ __align__(16) u16 As[64 * 72];
  __shared__ __align__(16) u16 Bs[64 * 72];
  const int tid = threadIdx.x;
  const int m0 = blockIdx.x * 64, n0 = blockIdx.y * 64;
  const int lane = tid & 63, wv = tid >> 6;
  const int fr = lane & 15, quad = lane >> 4;

  floatx4 acc[4];
#pragma unroll
  for (int i = 0; i < 4; ++i) acc[i] = (floatx4){0.f, 0.f, 0.f, 0.f};

  for (int kc = 0; kc < HH; kc += 64) {
    const u16* Ab = Ht + (u64)m0 * HH + kc;
#pragma unroll
    for (int it = 0; it < 2; ++it) {
      int linear = (it * 256 + tid) * 8;
      int r = linear >> 6, c = linear & 63;
      *(uint4*)&As[r * 72 + c] = *(const uint4*)(Ab + (u64)r * HH + c);
    }
    const u16* Bb = Wt + (u64)n0 * HH + kc;
#pragma unroll
    for (int it = 0; it < 2; ++it) {
      int linear = (it * 256 + tid) * 8;
      int n = linear >> 6, c = linear & 63;
      *(uint4*)&Bs[n * 72 + c] = *(const uint4*)(Bb + (u64)n * HH + c);
    }
    __syncthreads();
#pragma unroll
    for (int kk = 0; kk < 64; kk += 32) {
      frag8 bf = *(const frag8*)&Bs[(wv * 16 + fr) * 72 + kk + quad * 8];
#pragma unroll
      for (int i = 0; i < 4; ++i) {
        frag8 af = *(const frag8*)&As[(i * 16 + fr) * 72 + kk + quad * 8];
        acc[i] = __builtin_amdgcn_mfma_f32_16x16x32_bf16(af, bf, acc[i], 0, 0, 0);
      }
    }
    __syncthreads();
  }
  const int col = n0 + wv * 16 + fr;
#pragma unroll
  for (int i = 0; i < 4; ++i) {
#pragma unroll
    for (int r = 0; r < 4; ++r) {
      int m = m0 + i * 16 + quad * 4 + r;
      u64 off = (u64)m * HH + col;
      float z = b2f(Zs[off]);
      Zs[off] = f2b(tanhf(acc[i][r] + z));
    }
  }
}

// ---------------------------------------------------------------------------
// GEMM3: Y = Hs @ W_hy.  Hs bf16 [T*B][HH] (m = t*B + b), Wt bf16 [OO][HH].
// Output f32 scattered to out[b][t][col].
// ---------------------------------------------------------------------------
__global__ __launch_bounds__(256) void k_gemm_hy(const u16* __restrict__ Hs,
                                                 const u16* __restrict__ Wt,
                                                 float* __restrict__ out) {
  __shared__ __align__(16) u16 As[64 * 72];
  __shared__ __align__(16) u16 Bs[64 * 72];
  const int tid = threadIdx.x;
  const int m0 = blockIdx.x * 64, n0 = blockIdx.y * 64;
  const int lane = tid & 63, wv = tid >> 6;
  const int fr = lane & 15, quad = lane >> 4;

  floatx4 acc[4];
#pragma unroll
  for (int i = 0; i < 4; ++i) acc[i] = (floatx4){0.f, 0.f, 0.f, 0.f};

  for (int kc = 0; kc < HH; kc += 64) {
    const u16* Ab = Hs + (u64)m0 * HH + kc;
#pragma unroll
    for (int it = 0; it < 2; ++it) {
      int linear = (it * 256 + tid) * 8;
      int r = linear >> 6, c = linear & 63;
      *(uint4*)&As[r * 72 + c] = *(const uint4*)(Ab + (u64)r * HH + c);
    }
    const u16* Bb = Wt + (u64)n0 * HH + kc;
#pragma unroll
    for (int it = 0; it < 2; ++it) {
      int linear = (it * 256 + tid) * 8;
      int n = linear >> 6, c = linear & 63;
      *(uint4*)&Bs[n * 72 + c] = *(const uint4*)(Bb + (u64)n * HH + c);
    }
    __syncthreads();
#pragma unroll
    for (int kk = 0; kk < 64; kk += 32) {
      frag8 bf = *(const frag8*)&Bs[(wv * 16 + fr) * 72 + kk + quad * 8];
#pragma unroll
      for (int i = 0; i < 4; ++i) {
        frag8 af = *(const frag8*)&As[(i * 16 + fr) * 72 + kk + quad * 8];
        acc[i] = __builtin_amdgcn_mfma_f32_16x16x32_bf16(af, bf, acc[i], 0, 0, 0);
      }
    }
    __syncthreads();
  }
  const int col = n0 + wv * 16 + fr;
#pragma unroll
  for (int i = 0; i < 4; ++i) {
#pragma unroll
    for (int r = 0; r < 4; ++r) {
      int m = m0 + i * 16 + quad * 4 + r;
      int t = m >> 8;       // m / BB
      int b = m & (BB - 1); // m % BB
      out[(u64)b * (TT * OO) + (u64)t * OO + col] = acc[i][r];
    }
  }
}

extern "C" void kernel_launch(void* const* d_in, const int* in_sizes, int n_in,
                              void* d_out, int out_size, void* d_ws, size_t ws_size,
                              hipStream_t stream) {
  (void)in_sizes; (void)n_in; (void)out_size; (void)ws_size;
  const float* x    = (const float*)d_in[0];
  const float* h0   = (const float*)d_in[1];
  const float* w_xh = (const float*)d_in[2];
  const float* w_hh = (const float*)d_in[3];
  const float* w_hy = (const float*)d_in[4];
  float* out = (float*)d_out;

  // workspace layout (bf16 everywhere):
  //   S      : [TT+1][BB][HH]   state buffer (slot 0 = h0; slot t+1 = Z_t then h_{t+1})
  //   Wxh_t  : [HH][DD]
  //   Whh_t  : [HH][HH]
  //   Why_t  : [OO][HH]
  u16* S = (u16*)d_ws;
  u64 s_elems = (u64)(TT + 1) * BB * HH;
  u16* Wxh_t = S + s_elems;
  u16* Whh_t = Wxh_t + (u64)HH * DD;
  u16* Why_t = Whh_t + (u64)HH * HH;

  k_transpose<<<dim3((DD * HH + 255) / 256), dim3(256), 0, stream>>>(w_xh, Wxh_t, DD, HH);
  k_transpose<<<dim3((HH * HH + 255) / 256), dim3(256), 0, stream>>>(w_hh, Whh_t, HH, HH);
  k_transpose<<<dim3((HH * OO + 255) / 256), dim3(256), 0, stream>>>(w_hy, Why_t, HH, OO);
  k_init_s0<<<dim3(BB * HH / 256), dim3(256), 0, stream>>>(h0, S);

  k_gemm_xh<<<dim3((BB * TT) / 64, HH / 64), dim3(256), 0, stream>>>(x, Wxh_t, S);

  for (int t = 0; t < TT; ++t) {
    k_step<<<dim3(BB / 64, HH / 64), dim3(256), 0, stream>>>(
        S + (u64)t * BB * HH, Whh_t, S + (u64)(t + 1) * BB * HH);
  }

  k_gemm_hy<<<dim3((TT * BB) / 64, OO / 64), dim3(256), 0, stream>>>(
      S + (u64)BB * HH, Why_t, out);
  k_final_h<<<dim3(BB * HH / 256), dim3(256), 0, stream>>>(
      S + (u64)TT * BB * HH, out + (u64)BB * TT * OO);
}

// Round 2
// 7395.042 us; speedup vs baseline: 1.9256x; 1.9256x over previous
//
#include <hip/hip_runtime.h>
#include <hip/hip_bf16.h>

#define BB 256
#define TT 512
#define DD 512
#define HH 1024
#define OO 512

typedef unsigned short u16;
typedef unsigned int u32;
typedef unsigned long long u64;
typedef __attribute__((ext_vector_type(8))) short frag8;
typedef __attribute__((ext_vector_type(4))) float floatx4;

__device__ __forceinline__ u16 f2b(float f) {
  union { float f; u32 u; } v; v.f = f;
  u32 r = v.u + 0x7fffu + ((v.u >> 16) & 1u);
  return (u16)(r >> 16);
}
__device__ __forceinline__ float b2f(u16 b) {
  union { u32 u; float f; } v; v.u = ((u32)b) << 16; return v.f;
}
__device__ __forceinline__ float fast_tanh(float x) {
  // tanh(x) = 1 - 2/(exp(2x)+1); saturates correctly at +/-inf
  float e = __expf(2.0f * x);
  return 1.0f - 2.0f / (e + 1.0f);
}

// transpose f32 [K][N] -> bf16 [N][K]
__global__ void k_transpose(const float* __restrict__ src, u16* __restrict__ dst,
                            int K, int N) {
  int idx = blockIdx.x * 256 + threadIdx.x;
  if (idx >= K * N) return;
  int k = idx / N, n = idx - k * N;
  dst[(u64)n * K + k] = f2b(src[idx]);
}

__global__ void k_init_s0(const float* __restrict__ h0, u16* __restrict__ S) {
  int idx = blockIdx.x * 256 + threadIdx.x;
  if (idx < BB * HH) S[idx] = f2b(h0[idx]);
}

__global__ void k_final_h(const u16* __restrict__ Sl, float* __restrict__ out) {
  int idx = blockIdx.x * 256 + threadIdx.x;
  if (idx < BB * HH) out[idx] = b2f(Sl[idx]);
}

__global__ void k_zero_flags(int* __restrict__ flags, int n) {
  int idx = blockIdx.x * 256 + threadIdx.x;
  if (idx < n) flags[idx] = 0;
}

// ---------------------------------------------------------------------------
// GEMM1: Z = X @ W_xh.  X f32 [B*T, D] row-major (m = b*T + t).
// Wt bf16 [N=HH][K=DD].  Output scattered bf16 into S[t+1][b][col].
// ---------------------------------------------------------------------------
__global__ __launch_bounds__(256) void k_gemm_xh(const float* __restrict__ X,
                                                 const u16* __restrict__ Wt,
                                                 u16* __restrict__ S) {
  __shared__ __align__(16) u16 As[64 * 72];
  __shared__ __align__(16) u16 Bs[64 * 72];
  const int tid = threadIdx.x;
  const int m0 = blockIdx.x * 64, n0 = blockIdx.y * 64;
  const int lane = tid & 63, wv = tid >> 6;
  const int fr = lane & 15, quad = lane >> 4;

  floatx4 acc[4];
#pragma unroll
  for (int i = 0; i < 4; ++i) acc[i] = (floatx4){0.f, 0.f, 0.f, 0.f};

  for (int kc = 0; kc < DD; kc += 64) {
    const float* Ab = X + (u64)m0 * DD + kc;
#pragma unroll
    for (int it = 0; it < 4; ++it) {
      int linear = (it * 256 + tid) * 4;
      int r = linear >> 6, c = linear & 63;
      float4 v = *(const float4*)(Ab + (u64)r * DD + c);
      ushort4 o;
      o.x = f2b(v.x); o.y = f2b(v.y); o.z = f2b(v.z); o.w = f2b(v.w);
      *(ushort4*)&As[r * 72 + c] = o;
    }
    const u16* Bb = Wt + (u64)n0 * DD + kc;
#pragma unroll
    for (int it = 0; it < 2; ++it) {
      int linear = (it * 256 + tid) * 8;
      int n = linear >> 6, c = linear & 63;
      *(uint4*)&Bs[n * 72 + c] = *(const uint4*)(Bb + (u64)n * DD + c);
    }
    __syncthreads();
#pragma unroll
    for (int kk = 0; kk < 64; kk += 32) {
      frag8 bf = *(const frag8*)&Bs[(wv * 16 + fr) * 72 + kk + quad * 8];
#pragma unroll
      for (int i = 0; i < 4; ++i) {
        frag8 af = *(const frag8*)&As[(i * 16 + fr) * 72 + kk + quad * 8];
        acc[i] = __builtin_amdgcn_mfma_f32_16x16x32_bf16(af, bf, acc[i], 0, 0, 0);
      }
    }
    __syncthreads();
  }
  const int col = n0 + wv * 16 + fr;
#pragma unroll
  for (int i = 0; i < 4; ++i) {
#pragma unroll
    for (int r = 0; r < 4; ++r) {
      int m = m0 + i * 16 + quad * 4 + r;
      int t = m & (TT - 1);
      int b = m >> 9;  // m / TT
      S[((u64)(t + 1) * BB + b) * HH + col] = f2b(acc[i][r]);
    }
  }
}

// ---------------------------------------------------------------------------
// Persistent scan kernel: for t in 0..TT: S[t+1] = tanh(S[t] @ W_hh + S[t+1])
// Grid: 8 x 32 = 256 blocks (one per CU, co-resident). Block (mb,nb) owns the
// 32x32 output tile (rows mb*32, cols nb*32) for ALL steps. W_hh slice
// [nb*32..+32][1024] stays in LDS for the whole kernel. 4 waves K-split the
// 1024-deep dot product (256 each), fp32 LDS reduction, + Z, tanh.
// Cross-block dependency handled with agent-scope acquire/release flags.
// ---------------------------------------------------------------------------
__global__ __launch_bounds__(256) void k_scan(const u16* __restrict__ Whh_t,
                                              u16* __restrict__ S,
                                              int* __restrict__ flags) {
  extern __shared__ __align__(16) u16 smem[];
  u16* Ws = smem;                         // [32][1032] bf16  (66048 B)
  u16* As = smem + 32 * 1032;             // [32][1032] bf16  (66048 B)
  float* Red = (float*)(smem + 64 * 1032);  // [4][32][33] f32 (16896 B)

  const int tid = threadIdx.x;
  const int mb = blockIdx.x;   // 0..8  (row block)
  const int nb = blockIdx.y;   // 0..32 (col block)
  const int m0 = mb * 32, n0 = nb * 32;
  const int lane = tid & 63, wv = tid >> 6;
  const int fr = lane & 15, q = lane >> 4;
  const int kbase = wv * 256;

  // Load resident W slice: rows n0..n0+32 of Whh_t [n][k]
  {
    const u16* Wb = Whh_t + (u64)n0 * HH;
#pragma unroll
    for (int it = 0; it < 16; ++it) {
      int linear = (it * 256 + tid) * 8;
      int r = linear >> 10, c = linear & 1023;
      *(uint4*)&Ws[r * 1032 + c] = *(const uint4*)(Wb + (u64)r * HH + c);
    }
  }
  __syncthreads();

  for (int t = 0; t < TT; ++t) {
    if (t > 0) {
      if (tid == 0) {
        while (__hip_atomic_load(&flags[(t - 1) * 8 + mb], __ATOMIC_ACQUIRE,
                                 __HIP_MEMORY_SCOPE_AGENT) < 32) {
          __builtin_amdgcn_s_sleep(2);
        }
      }
      __syncthreads();
    }

    // Stage A = S[t] rows m0..m0+32 into LDS
    const u16* Ab = S + (u64)t * BB * HH + (u64)m0 * HH;
#pragma unroll
    for (int it = 0; it < 16; ++it) {
      int linear = (it * 256 + tid) * 8;
      int r = linear >> 10, c = linear & 1023;
      *(uint4*)&As[r * 1032 + c] = *(const uint4*)(Ab + (u64)r * HH + c);
    }
    __syncthreads();

    floatx4 acc[2][2];
#pragma unroll
    for (int i = 0; i < 2; ++i)
#pragma unroll
      for (int j = 0; j < 2; ++j) acc[i][j] = (floatx4){0.f, 0.f, 0.f, 0.f};

#pragma unroll
    for (int kt = 0; kt < 8; ++kt) {
      int k = kbase + kt * 32 + q * 8;
      frag8 a0 = *(const frag8*)&As[fr * 1032 + k];
      frag8 a1 = *(const frag8*)&As[(16 + fr) * 1032 + k];
      frag8 b0 = *(const frag8*)&Ws[fr * 1032 + k];
      frag8 b1 = *(const frag8*)&Ws[(16 + fr) * 1032 + k];
      acc[0][0] = __builtin_amdgcn_mfma_f32_16x16x32_bf16(a0, b0, acc[0][0], 0, 0, 0);
      acc[0][1] = __builtin_amdgcn_mfma_f32_16x16x32_bf16(a0, b1, acc[0][1], 0, 0, 0);
      acc[1][0] = __builtin_amdgcn_mfma_f32_16x16x32_bf16(a1, b0, acc[1][0], 0, 0, 0);
      acc[1][1] = __builtin_amdgcn_mfma_f32_16x16x32_bf16(a1, b1, acc[1][1], 0, 0, 0);
    }

    // Write per-wave partials to LDS: Red[wv][row][col]
#pragma unroll
    for (int im = 0; im < 2; ++im)
#pragma unroll
      for (int in = 0; in < 2; ++in)
#pragma unroll
        for (int r = 0; r < 4; ++r) {
          int row = im * 16 + q * 4 + r;
          int col = in * 16 + fr;
          Red[(wv * 32 + row) * 33 + col] = acc[im][in][r];
        }
    __syncthreads();

    // Reduce 4 partials, add Z (pre-filled in S[t+1]), tanh, store bf16
    u16* Sout = S + (u64)(t + 1) * BB * HH + (u64)m0 * HH + n0;
#pragma unroll
    for (int i = 0; i < 4; ++i) {
      int elem = i * 256 + tid;
      int r = elem >> 5, c = elem & 31;
      float v = Red[(0 * 32 + r) * 33 + c] + Red[(1 * 32 + r) * 33 + c] +
                Red[(2 * 32 + r) * 33 + c] + Red[(3 * 32 + r) * 33 + c];
      u64 off = (u64)r * HH + c;
      float z = b2f(Sout[off]);
      Sout[off] = f2b(fast_tanh(v + z));
    }
    __syncthreads();  // all stores drained (vmcnt(0) before barrier)

    if (tid == 0) {
      __hip_atomic_fetch_add(&flags[t * 8 + mb], 1, __ATOMIC_RELEASE,
                             __HIP_MEMORY_SCOPE_AGENT);
    }
  }
}

// ---------------------------------------------------------------------------
// GEMM3: Y = Hs @ W_hy.  Hs bf16 [T*B][HH] (m = t*B + b), Wt bf16 [OO][HH].
// ---------------------------------------------------------------------------
__global__ __launch_bounds__(256) void k_gemm_hy(const u16* __restrict__ Hs,
                                                 const u16* __restrict__ Wt,
                                                 float* __restrict__ out) {
  __shared__ __align__(16) u16 As[64 * 72];
  __shared__ __align__(16) u16 Bs[64 * 72];
  const int tid = threadIdx.x;
  const int m0 = blockIdx.x * 64, n0 = blockIdx.y * 64;
  const int lane = tid & 63, wv = tid >> 6;
  const int fr = lane & 15, quad = lane >> 4;

  floatx4 acc[4];
#pragma unroll
  for (int i = 0; i < 4; ++i) acc[i] = (floatx4){0.f, 0.f, 0.f, 0.f};

  for (int kc = 0; kc < HH; kc += 64) {
    const u16* Ab = Hs + (u64)m0 * HH + kc;
#pragma unroll
    for (int it = 0; it < 2; ++it) {
      int linear = (it * 256 + tid) * 8;
      int r = linear >> 6, c = linear & 63;
      *(uint4*)&As[r * 72 + c] = *(const uint4*)(Ab + (u64)r * HH + c);
    }
    const u16* Bb = Wt + (u64)n0 * HH + kc;
#pragma unroll
    for (int it = 0; it < 2; ++it) {
      int linear = (it * 256 + tid) * 8;
      int n = linear >> 6, c = linear & 63;
      *(uint4*)&Bs[n * 72 + c] = *(const uint4*)(Bb + (u64)n * HH + c);
    }
    __syncthreads();
#pragma unroll
    for (int kk = 0; kk < 64; kk += 32) {
      frag8 bf = *(const frag8*)&Bs[(wv * 16 + fr) * 72 + kk + quad * 8];
#pragma unroll
      for (int i = 0; i < 4; ++i) {
        frag8 af = *(const frag8*)&As[(i * 16 + fr) * 72 + kk + quad * 8];
        acc[i] = __builtin_amdgcn_mfma_f32_16x16x32_bf16(af, bf, acc[i], 0, 0, 0);
      }
    }
    __syncthreads();
  }
  const int col = n0 + wv * 16 + fr;
#pragma unroll
  for (int i = 0; i < 4; ++i) {
#pragma unroll
    for (int r = 0; r < 4; ++r) {
      int m = m0 + i * 16 + quad * 4 + r;
      int t = m >> 8;       // m / BB
      int b = m & (BB - 1); // m % BB
      out[(u64)b * (TT * OO) + (u64)t * OO + col] = acc[i][r];
    }
  }
}

extern "C" void kernel_launch(void* const* d_in, const int* in_sizes, int n_in,
                              void* d_out, int out_size, void* d_ws, size_t ws_size,
                              hipStream_t stream) {
  (void)in_sizes; (void)n_in; (void)out_size; (void)ws_size;
  const float* x    = (const float*)d_in[0];
  const float* h0   = (const float*)d_in[1];
  const float* w_xh = (const float*)d_in[2];
  const float* w_hh = (const float*)d_in[3];
  const float* w_hy = (const float*)d_in[4];
  float* out = (float*)d_out;

  // workspace layout (bf16):
  //   S     : [TT+1][BB][HH]  state (slot 0 = h0; slot t+1 = Z_t then h_{t+1})
  //   Wxh_t : [HH][DD]   (aliased by scan flags after gemm_xh is done)
  //   Whh_t : [HH][HH]
  //   Why_t : [OO][HH]
  u16* S = (u16*)d_ws;
  u64 s_elems = (u64)(TT + 1) * BB * HH;
  u16* Wxh_t = S + s_elems;
  u16* Whh_t = Wxh_t + (u64)HH * DD;
  u16* Why_t = Whh_t + (u64)HH * HH;
  int* flags = (int*)Wxh_t;  // 512*8 ints; Wxh_t dead after gemm_xh
  const int n_flags = TT * 8;

  k_transpose<<<dim3((DD * HH + 255) / 256), dim3(256), 0, stream>>>(w_xh, Wxh_t, DD, HH);
  k_transpose<<<dim3((HH * HH + 255) / 256), dim3(256), 0, stream>>>(w_hh, Whh_t, HH, HH);
  k_transpose<<<dim3((HH * OO + 255) / 256), dim3(256), 0, stream>>>(w_hy, Why_t, HH, OO);
  k_init_s0<<<dim3(BB * HH / 256), dim3(256), 0, stream>>>(h0, S);

  k_gemm_xh<<<dim3((BB * TT) / 64, HH / 64), dim3(256), 0, stream>>>(x, Wxh_t, S);

  k_zero_flags<<<dim3((n_flags + 255) / 256), dim3(256), 0, stream>>>(flags, n_flags);

  const int scan_lds = (32 * 1032 + 32 * 1032) * 2 + 4 * 32 * 33 * 4;  // 148992 B
  hipFuncSetAttribute((const void*)k_scan,
                      hipFuncAttributeMaxDynamicSharedMemorySize, scan_lds);
  k_scan<<<dim3(8, 32), dim3(256), scan_lds, stream>>>(Whh_t, S, flags);

  k_gemm_hy<<<dim3((TT * BB) / 64, OO / 64), dim3(256), 0, stream>>>(
      S + (u64)BB * HH, Why_t, out);
  k_final_h<<<dim3(BB * HH / 256), dim3(256), 0, stream>>>(
      S + (u64)TT * BB * HH, out + (u64)BB * TT * OO);
}